// Round 4
// baseline (2402.645 us; speedup 1.0000x reference)
//
#include <hip/hip_runtime.h>

typedef unsigned short u16;
typedef __bf16 bf16x8 __attribute__((ext_vector_type(8)));
typedef float f32x4 __attribute__((ext_vector_type(4)));

#define BB   2
#define SS   2048
#define EE   2048
#define HH   2688
#define NHH  4
#define DHH  672
#define NPHH 672
#define H2   5376
#define H3   8064

__device__ __forceinline__ float b2f(u16 u) {
  union { unsigned int i; float f; } c; c.i = ((unsigned int)u) << 16; return c.f;
}
__device__ __forceinline__ u16 f2b(float f) {
  union { float f; unsigned int i; } c; c.f = f;
  unsigned int i = c.i;
  return (u16)((i + 0x7FFFu + ((i >> 16) & 1u)) >> 16);
}
__device__ __forceinline__ float silu_f(float x) { return x / (1.f + __expf(-x)); }
__device__ __forceinline__ float logsig_f(float f) {
  return (f >= 0.f) ? -log1pf(__expf(-f)) : (f - log1pf(__expf(f)));
}

// dtype sniffer: 1 if buffer holds fp32 (N(0,1)-scale) data, 0 if bf16.
__device__ __forceinline__ int sniff_f32(const u16* xp) {
  int c = 0;
#pragma unroll
  for (int i = 0; i < 64; i++) {
    unsigned e = (xp[2 * i] >> 7) & 0xFFu;
    c += (e >= 100u && e <= 141u) ? 1 : 0;
  }
  return c < 32;
}
__device__ __forceinline__ float ldin(const void* p, long i, int f) {
  return f ? ((const float*)p)[i] : b2f(((const u16*)p)[i]);
}
__device__ __forceinline__ void stage8(u16* dst, const void* base, long elem,
                                       bool f32src, bool valid) {
  if (!valid) { *reinterpret_cast<uint4*>(dst) = make_uint4(0u,0u,0u,0u); return; }
  if (!f32src) {
    *reinterpret_cast<uint4*>(dst) = *reinterpret_cast<const uint4*>((const u16*)base + elem);
  } else {
    const float* f = (const float*)base + elem;
    float4 a = *reinterpret_cast<const float4*>(f);
    float4 b = *reinterpret_cast<const float4*>(f + 4);
    u16 t[8] = {f2b(a.x), f2b(a.y), f2b(a.z), f2b(a.w),
                f2b(b.x), f2b(b.y), f2b(b.z), f2b(b.w)};
    *reinterpret_cast<uint4*>(dst) = *reinterpret_cast<uint4*>(t);
  }
}

// ---------------------------------------------------------------------------
// NT GEMM: C[i,j] = sum_k A[i,k] * Bt[j,k]
// MODE 0 plain; MODE 1 QK epilogue (mask+exp, skip blocks above diag);
// MODE 2 PV epilogue (row scale, causal K-cap)
// OUTF32: store fp32 instead of bf16
// ---------------------------------------------------------------------------
template <int MODE, int SNIFFA, int OUTF32>
__global__ __launch_bounds__(256) void gemm_nt(
    const void* __restrict__ A, const u16* __restrict__ Bt, void* __restrict__ Cp,
    int M, int N, int K, int lda, int ldb, int ldc,
    const float* __restrict__ aux1, const float* __restrict__ aux2,
    int causal, const u16* __restrict__ sx)
{
  __shared__ __align__(16) u16 As[128][32];
  __shared__ __align__(16) u16 Bs[128][32];
  bool af32 = false;
  if (SNIFFA) af32 = (sniff_f32(sx) != 0);

  int m0 = blockIdx.y * 128, n0 = blockIdx.x * 128;
  int t = threadIdx.x, lane = t & 63, wid = t >> 6;
  int wm = (wid >> 1) * 64, wn = (wid & 1) * 64;
  int l15 = lane & 15, quad = lane >> 4;

  f32x4 acc[4][4];
#pragma unroll
  for (int i = 0; i < 4; i++)
#pragma unroll
    for (int j = 0; j < 4; j++) acc[i][j] = (f32x4){0.f,0.f,0.f,0.f};

  bool skip = (MODE == 1) && (n0 > m0 + 127);
  int Keff = K;
  if (MODE == 2 && causal) Keff = min(K, m0 + 128);

  if (!skip) {
    int r = t >> 2, seg = (t & 3) * 8;
    for (int k0 = 0; k0 < Keff; k0 += 32) {
      __syncthreads();
#pragma unroll
      for (int i = 0; i < 2; i++) {
        int rr = r + i * 64;
        int ga = m0 + rr;
        stage8(&As[rr][seg], A, (long)ga * lda + k0 + seg, af32, ga < M);
        int gb = n0 + rr;
        stage8(&Bs[rr][seg], Bt, (long)gb * ldb + k0 + seg, false, gb < N);
      }
      __syncthreads();
      bf16x8 af[4], bfr[4];
#pragma unroll
      for (int i = 0; i < 4; i++) {
        af[i]  = *reinterpret_cast<const bf16x8*>(&As[wm + i * 16 + l15][quad * 8]);
        bfr[i] = *reinterpret_cast<const bf16x8*>(&Bs[wn + i * 16 + l15][quad * 8]);
      }
#pragma unroll
      for (int i = 0; i < 4; i++)
#pragma unroll
        for (int j = 0; j < 4; j++)
          acc[i][j] = __builtin_amdgcn_mfma_f32_16x16x32_bf16(af[i], bfr[j], acc[i][j], 0, 0, 0);
    }
  }

  const float rs = 0.03857583749f;  // 1/sqrt(672)
#pragma unroll
  for (int i = 0; i < 4; i++) {
#pragma unroll
    for (int j = 0; j < 4; j++) {
      int col = n0 + wn + j * 16 + l15;
      if (col >= N) continue;
#pragma unroll
      for (int rr = 0; rr < 4; rr++) {
        int row = m0 + wm + i * 16 + quad * 4 + rr;
        if (row >= M) continue;
        float v = acc[i][j][rr];
        if (MODE == 1) v = (col <= row) ? v * rs * __expf(aux1[col] - aux2[row]) : 0.f;
        else if (MODE == 2) v = v * aux1[row];
        if (OUTF32) ((float*)Cp)[(long)row * ldc + col] = v;
        else        ((u16*)Cp)[(long)row * ldc + col] = f2b(v);
      }
    }
  }
}

// ---------------------------------------------------------------------------
__global__ __launch_bounds__(256) void transpose_any(
    const void* __restrict__ in, u16* __restrict__ out, int R, int C,
    const u16* __restrict__ sx, int dosniff)
{
  __shared__ u16 tile[64][65];
  bool f32 = dosniff && (sniff_f32(sx) != 0);
  const u16* in16 = (const u16*)in;
  const float* inf = (const float*)in;
  int r0 = blockIdx.y * 64, c0 = blockIdx.x * 64;
  int t = threadIdx.x;
  for (int idx = t; idx < 64 * 64; idx += 256) {
    int r = idx >> 6, c = idx & 63;
    int rr = r0 + r, cc = c0 + c;
    u16 v = 0;
    if (rr < R && cc < C) {
      long off = (long)rr * C + cc;
      v = f32 ? f2b(inf[off]) : in16[off];
    }
    tile[r][c] = v;
  }
  __syncthreads();
  for (int idx = t; idx < 64 * 64; idx += 256) {
    int r = idx & 63, c = idx >> 6;
    int rr = r0 + r, cc = c0 + c;
    if (rr < R && cc < C) out[(long)cc * R + rr] = tile[r][c];
  }
}

// ---------------------------------------------------------------------------
__global__ __launch_bounds__(256) void conv_silu(
    const u16* __restrict__ xinner, const void* __restrict__ cw,
    const void* __restrict__ cb, u16* __restrict__ xca, const u16* __restrict__ sx)
{
  int f = sniff_f32(sx);
  long idx = (long)blockIdx.x * 256 + threadIdx.x;
  if (idx >= (long)BB * SS * HH) return;
  int h = (int)(idx % HH);
  long bs = idx / HH;
  int s = (int)(bs % SS);
  float acc = ldin(cb, h, f);
#pragma unroll
  for (int w = 0; w < 4; w++) {
    int ss = s + w - 3;
    if (ss >= 0) acc += b2f(xinner[(bs - s + ss) * H2 + h]) * ldin(cw, w * HH + h, f);
  }
  xca[idx] = f2b(silu_f(acc));
}

// ---------------------------------------------------------------------------
__global__ __launch_bounds__(256) void headwise_qkv(
    const u16* __restrict__ xinner, const u16* __restrict__ xca,
    const void* __restrict__ Wq, const void* __restrict__ Wk, const void* __restrict__ Wv,
    u16* __restrict__ q, u16* __restrict__ k, u16* __restrict__ v,
    const u16* __restrict__ sx)
{
  int f = sniff_f32(sx);
  int idx = blockIdx.x * 256 + threadIdx.x;
  if (idx >= BB * SS * NPHH) return;
  int nph = idx % NPHH;
  int bs = idx / NPHH;
  int cbase = nph * 4;
  float xa[4], xm[4];
  const u16* xcap = xca + (long)bs * HH + cbase;
  const u16* xmp  = xinner + (long)bs * H2 + cbase;
#pragma unroll
  for (int d = 0; d < 4; d++) { xa[d] = b2f(xcap[d]); xm[d] = b2f(xmp[d]); }
  int n = cbase / DHH;
  int d0 = cbase - n * DHH;
  long obase = (((long)(bs / SS) * NHH + n) * SS + (bs % SS)) * DHH + d0;
#pragma unroll
  for (int o = 0; o < 4; o++) {
    float aq = 0.f, ak = 0.f, av = 0.f;
#pragma unroll
    for (int d = 0; d < 4; d++) {
      aq += xa[d] * ldin(Wq, (nph * 4 + d) * 4 + o, f);
      ak += xa[d] * ldin(Wk, (nph * 4 + d) * 4 + o, f);
      av += xm[d] * ldin(Wv, (nph * 4 + d) * 4 + o, f);
    }
    q[obase + o] = f2b(aq);
    k[obase + o] = f2b(ak);
    v[obase + o] = f2b(av);
  }
}

// ---------------------------------------------------------------------------
__global__ __launch_bounds__(256) void gates_kernel(
    const u16* __restrict__ q, const u16* __restrict__ k, const u16* __restrict__ v,
    const void* __restrict__ Wig, const void* __restrict__ big,
    const void* __restrict__ Wfg, const void* __restrict__ bfg,
    float* __restrict__ ipre, float* __restrict__ fpre, const u16* __restrict__ sx)
{
  int f = sniff_f32(sx);
  int wave = (blockIdx.x * 256 + threadIdx.x) >> 6;
  int lane = threadIdx.x & 63;
  if (wave >= BB * SS) return;
  int b = wave / SS, s = wave % SS;
  float ai[4] = {0,0,0,0}, af[4] = {0,0,0,0};
  for (int c = lane; c < HH; c += 64) {
    int n = c / DHH, d = c % DHH;
    long qi = (((long)b * NHH + n) * SS + s) * DHH + d;
    float qv = b2f(q[qi]), kv = b2f(k[qi]), vv = b2f(v[qi]);
#pragma unroll
    for (int nn = 0; nn < 4; nn++) {
      ai[nn] += qv * ldin(Wig, c * 4 + nn, f) + kv * ldin(Wig, (HH + c) * 4 + nn, f) +
                vv * ldin(Wig, (2 * HH + c) * 4 + nn, f);
      af[nn] += qv * ldin(Wfg, c * 4 + nn, f) + kv * ldin(Wfg, (HH + c) * 4 + nn, f) +
                vv * ldin(Wfg, (2 * HH + c) * 4 + nn, f);
    }
  }
#pragma unroll
  for (int off = 32; off > 0; off >>= 1) {
#pragma unroll
    for (int nn = 0; nn < 4; nn++) {
      ai[nn] += __shfl_down(ai[nn], off);
      af[nn] += __shfl_down(af[nn], off);
    }
  }
  if (lane == 0) {
#pragma unroll
    for (int nn = 0; nn < 4; nn++) {
      ipre[((long)b * NHH + nn) * SS + s] = ai[nn] + ldin(big, nn, f);
      fpre[((long)b * NHH + nn) * SS + s] = af[nn] + ldin(bfg, nn, f);
    }
  }
}

// ---------------------------------------------------------------------------
__global__ __launch_bounds__(1024) void scan_kernel(
    const float* __restrict__ ipre, const float* __restrict__ fpre,
    float* __restrict__ avec, float* __restrict__ rmaxvec, float* __restrict__ mvec)
{
  __shared__ float buf[2][SS];
  __shared__ float cssave[SS];
  int bn = blockIdx.x;
  const float* fp = fpre + (long)bn * SS;
  const float* ip = ipre + (long)bn * SS;
  int t = threadIdx.x;
  for (int i = t; i < SS; i += 1024) buf[0][i] = logsig_f(fp[i]);
  __syncthreads();
  int src = 0;
  for (int off = 1; off < SS; off <<= 1) {
    int dst = 1 - src;
    for (int i = t; i < SS; i += 1024) {
      float x = buf[src][i];
      if (i >= off) x += buf[src][i - off];
      buf[dst][i] = x;
    }
    __syncthreads();
    src = dst;
  }
  for (int i = t; i < SS; i += 1024) {
    float cs = buf[src][i];
    cssave[i] = cs;
    float a = ip[i] - cs;
    avec[(long)bn * SS + i] = a;
    buf[src][i] = a;
  }
  __syncthreads();
  for (int off = 1; off < SS; off <<= 1) {
    int dst = 1 - src;
    for (int i = t; i < SS; i += 1024) {
      float x = buf[src][i];
      if (i >= off) x = fmaxf(x, buf[src][i - off]);
      buf[dst][i] = x;
    }
    __syncthreads();
    src = dst;
  }
  for (int i = t; i < SS; i += 1024) {
    rmaxvec[(long)bn * SS + i] = buf[src][i];
    mvec[(long)bn * SS + i] = cssave[i] + buf[src][i];
  }
}

// ---------------------------------------------------------------------------
__global__ __launch_bounds__(256) void rowsum_kernel(
    const u16* __restrict__ P, const float* __restrict__ mvec, float* __restrict__ invn)
{
  int row = (blockIdx.x * 256 + threadIdx.x) >> 6;
  int lane = threadIdx.x & 63;
  if (row >= SS) return;
  const u16* pr = P + (long)row * SS;
  float s = 0.f;
  for (int j = lane; j < SS; j += 64) s += b2f(pr[j]);
#pragma unroll
  for (int off = 32; off > 0; off >>= 1) s += __shfl_down(s, off);
  if (lane == 0) {
    float n = fmaxf(fabsf(s), __expf(-mvec[row]));
    invn[row] = 1.f / (n + 1e-6f);
  }
}

// ---------------------------------------------------------------------------
__global__ __launch_bounds__(256) void ln_skip_gate(
    const u16* __restrict__ h, const u16* __restrict__ xca,
    const u16* __restrict__ xinner, const void* __restrict__ normw,
    const void* __restrict__ skipw, u16* __restrict__ hs, const u16* __restrict__ sx)
{
  int f = sniff_f32(sx);
  int row = (blockIdx.x * 256 + threadIdx.x) >> 6;
  int lane = threadIdx.x & 63;
  if (row >= BB * NHH * SS) return;
  int s = row % SS;
  int n = (row / SS) % NHH;
  int b = row / (SS * NHH);
  const u16* hr = h + (long)row * DHH;
  float sum = 0.f, ss = 0.f;
  float vals[11];
  int cnt = 0;
  for (int d = lane; d < DHH; d += 64) {
    float x = b2f(hr[d]);
    vals[cnt++] = x; sum += x; ss += x * x;
  }
#pragma unroll
  for (int off = 32; off > 0; off >>= 1) { sum += __shfl_down(sum, off); ss += __shfl_down(ss, off); }
  sum = __shfl(sum, 0); ss = __shfl(ss, 0);
  float mu = sum / (float)DHH;
  float var = ss / (float)DHH - mu * mu;
  float rstd = rsqrtf(var + 1e-5f);
  long bs = (long)b * SS + s;
  cnt = 0;
  for (int d = lane; d < DHH; d += 64) {
    int c = n * DHH + d;
    float hn = (vals[cnt++] - mu) * rstd * ldin(normw, c, f);
    float hskip = hn + ldin(skipw, c, f) * b2f(xca[bs * HH + c]);
    float z = b2f(xinner[bs * H2 + HH + c]);
    hs[bs * HH + c] = f2b(hskip * silu_f(z));
  }
}

// ---------------------------------------------------------------------------
__global__ __launch_bounds__(256) void fill_sentinel(float* out, float v, long n) {
  long i = (long)blockIdx.x * 256 + threadIdx.x;
  if (i < n) out[i] = v;
}

// ---------------------------------------------------------------------------
extern "C" void kernel_launch(void* const* d_in, const int* in_sizes, int n_in,
                              void* d_out, int out_size, void* d_ws, size_t ws_size,
                              hipStream_t stream)
{
  const u16* sx      = (const u16*)d_in[0];
  const void* x      = d_in[0];
  const void* W_in   = d_in[1];
  const void* conv_w = d_in[2];
  const void* conv_b = d_in[3];
  const void* Wq     = d_in[4];
  const void* Wk     = d_in[5];
  const void* Wv     = d_in[6];
  const void* W_ig   = d_in[7];
  const void* b_ig   = d_in[8];
  const void* W_fg   = d_in[9];
  const void* b_fg   = d_in[10];
  const void* norm_w = d_in[11];
  const void* skipw  = d_in[12];
  const void* W_out  = d_in[13];
  float* out = (float*)d_out;      // reference returns float32
  const long SD = (long)SS * DHH;

  u16* ws = (u16*)d_ws;
  size_t off = 0;
  auto alloc = [&](size_t n) { u16* p = ws + off; off += n; return p; };
  u16* x_inner = alloc((size_t)4096 * H2);
  u16* xca     = alloc((size_t)4096 * HH);
  u16* qb      = alloc((size_t)8 * SD);   // W_inT first, then q, then hs
  u16* kb      = alloc((size_t)8 * SD);   // k, then h
  u16* vb      = alloc((size_t)8 * SD);   // v, then W_outT
  u16* vt      = alloc((size_t)DHH * SS); // per-bn v^T
  u16* Pb      = alloc((size_t)SS * SS);  // per-bn P
  float* fb = (float*)(ws + off);
  float* ipre    = fb;
  float* fpre    = ipre + 16384;
  float* avec    = fpre + 16384;
  float* rmaxvec = avec + 16384;
  float* mvec    = rmaxvec + 16384;
  float* invn    = mvec + 16384;
  size_t need = off * 2 + (size_t)(6 * 16384) * 4;
  long outn = (long)4096 * EE;

  if (ws_size < need) {  // diagnostic: encode ws_size (MiB/100) into output
    fill_sentinel<<<dim3((outn + 255) / 256), 256, 0, stream>>>(
        out, 200.f + 0.01f * (float)(ws_size >> 20), outn);
    return;
  }

  u16* W_inT  = qb;   // 5376 x 2048 == qb size exactly
  u16* W_outT = vb;   // 2048 x 2688 (written after bn loop)
  u16* hbuf   = kb;   // h overwrites k per-bn after k's last use
  u16* hsbuf  = qb;   // hs overwrites q after bn loop

  transpose_any<<<dim3(84, 32, 1), 256, 0, stream>>>(W_in, W_inT, EE, H2, sx, 1);
  gemm_nt<0, 1, 0><<<dim3(42, 32, 1), 256, 0, stream>>>(
      x, W_inT, x_inner, 4096, H2, EE, EE, EE, H2, nullptr, nullptr, 0, sx);
  conv_silu<<<dim3(43008, 1, 1), 256, 0, stream>>>(x_inner, conv_w, conv_b, xca, sx);
  headwise_qkv<<<dim3(10752, 1, 1), 256, 0, stream>>>(
      x_inner, xca, Wq, Wk, Wv, qb, kb, vb, sx);
  gates_kernel<<<dim3(1024, 1, 1), 256, 0, stream>>>(
      qb, kb, vb, W_ig, b_ig, W_fg, b_fg, ipre, fpre, sx);
  scan_kernel<<<dim3(8, 1, 1), 1024, 0, stream>>>(ipre, fpre, avec, rmaxvec, mvec);

  for (int bn = 0; bn < 8; bn++) {
    transpose_any<<<dim3(11, 32, 1), 256, 0, stream>>>(
        vb + bn * SD, vt, SS, DHH, nullptr, 0);
    gemm_nt<1, 0, 0><<<dim3(16, 16, 1), 256, 0, stream>>>(
        qb + bn * SD, kb + bn * SD, Pb, SS, SS, DHH, DHH, DHH, SS,
        avec + bn * SS, rmaxvec + bn * SS, 0, nullptr);
    rowsum_kernel<<<dim3(512, 1, 1), 256, 0, stream>>>(Pb, mvec + bn * SS, invn + bn * SS);
    gemm_nt<2, 0, 0><<<dim3(6, 16, 1), 256, 0, stream>>>(
        Pb, vt, hbuf + bn * SD, SS, DHH, SS, SS, SS, DHH,
        invn + bn * SS, nullptr, 1, nullptr);
  }

  transpose_any<<<dim3(32, 42, 1), 256, 0, stream>>>(W_out, W_outT, HH, EE, sx, 1);
  ln_skip_gate<<<dim3(4096, 1, 1), 256, 0, stream>>>(
      hbuf, xca, x_inner, norm_w, skipw, hsbuf, sx);
  gemm_nt<0, 0, 1><<<dim3(16, 32, 1), 256, 0, stream>>>(
      hsbuf, W_outT, out, 4096, EE, HH, HH, HH, EE, nullptr, nullptr, 0, nullptr);
}

// Round 5
// 1231.691 us; speedup vs baseline: 1.9507x; 1.9507x over previous
//
#include <hip/hip_runtime.h>

typedef unsigned short u16;
typedef unsigned int u32;
typedef __bf16 bf16x8 __attribute__((ext_vector_type(8)));
typedef float f32x4 __attribute__((ext_vector_type(4)));

#define BB   2
#define SS   2048
#define EE   2048
#define HH   2688
#define NHH  4
#define DHH  672
#define NPHH 672
#define H2   5376

__device__ __forceinline__ float b2f(u16 u) {
  union { unsigned int i; float f; } c; c.i = ((unsigned int)u) << 16; return c.f;
}
__device__ __forceinline__ u16 f2b(float f) {
  union { float f; unsigned int i; } c; c.f = f;
  unsigned int i = c.i;
  return (u16)((i + 0x7FFFu + ((i >> 16) & 1u)) >> 16);
}
__device__ __forceinline__ float silu_f(float x) { return x / (1.f + __expf(-x)); }
__device__ __forceinline__ float logsig_f(float f) {
  return (f >= 0.f) ? -log1pf(__expf(-f)) : (f - log1pf(__expf(f)));
}
__device__ __forceinline__ int sniff_f32(const u16* xp) {
  int c = 0;
#pragma unroll
  for (int i = 0; i < 64; i++) {
    unsigned e = (xp[2 * i] >> 7) & 0xFFu;
    c += (e >= 100u && e <= 141u) ? 1 : 0;
  }
  return c < 32;
}
__device__ __forceinline__ float ldin(const void* p, long i, int f) {
  return f ? ((const float*)p)[i] : b2f(((const u16*)p)[i]);
}

// async global->LDS, 16B per lane; dst is wave-uniform base, HW adds lane*16B
__device__ __forceinline__ void gl2lds16(const u16* g, u16* s) {
  __builtin_amdgcn_global_load_lds(
      (const __attribute__((address_space(1))) u32*)g,
      (__attribute__((address_space(3))) u32*)s, 16, 0, 0);
}

// ---------------------------------------------------------------------------
// NT GEMM (bf16 A,B): C[i,j] = sum_k A[i,k]*Bt[j,k]
// MODE 0 plain; MODE 1 QK epilogue (skip above-diag blocks, no stores there);
// MODE 2 PV epilogue (row scale, causal K-cap). OUTF32: fp32 store.
// Staging: global_load_lds width=16 (m97 pattern). M must be mult of 128; N may
// be partial (OOB B rows read in-bounds ws garbage; their cols are never stored).
// ---------------------------------------------------------------------------
template <int MODE, int OUTF32>
__global__ __launch_bounds__(256) void gemm_nt(
    const u16* __restrict__ A, const u16* __restrict__ Bt, void* __restrict__ Cp,
    int M, int N, int K, int lda, int ldb, int ldc,
    long sA, long sB, long sC,
    const float* __restrict__ aux1, const float* __restrict__ aux2,
    int auxStride, int causal)
{
  __shared__ __align__(16) u16 As[128 * 32];
  __shared__ __align__(16) u16 Bs[128 * 32];
  int m0 = blockIdx.y * 128, n0 = blockIdx.x * 128;
  if (MODE == 1 && n0 > m0 + 127) return;
  int bz = blockIdx.z;
  A  += (long)bz * sA;
  Bt += (long)bz * sB;
  const float* a1 = aux1 ? aux1 + (long)bz * auxStride : nullptr;
  const float* a2 = aux2 ? aux2 + (long)bz * auxStride : nullptr;
  u16*   C16 = (u16*)Cp + (long)bz * sC;
  float* C32 = (float*)Cp + (long)bz * sC;

  int t = threadIdx.x, lane = t & 63, wid = t >> 6;
  int wm = (wid >> 1) * 64, wn = (wid & 1) * 64;
  int l15 = lane & 15, quad = lane >> 4;

  int srow = wid * 16 + (lane >> 2);     // wave-chunk row 0..63
  int scol = (lane & 3) * 8;             // u16 col within 32-wide tile row
  const u16* pA0 = A + (long)(m0 + srow) * lda + scol;
  const u16* pA1 = pA0 + (long)64 * lda;
  const u16* pB0 = Bt + (long)(n0 + srow) * ldb + scol;
  const u16* pB1 = pB0 + (long)64 * ldb;
  u16* dA = As + wid * 512;
  u16* dB = Bs + wid * 512;

  f32x4 acc[4][4];
#pragma unroll
  for (int i = 0; i < 4; i++)
#pragma unroll
    for (int j = 0; j < 4; j++) acc[i][j] = (f32x4){0.f, 0.f, 0.f, 0.f};

  int Keff = (MODE == 2 && causal) ? min(K, m0 + 128) : K;

  for (int k0 = 0; k0 < Keff; k0 += 32) {
    __syncthreads();
    gl2lds16(pA0 + k0, dA);
    gl2lds16(pA1 + k0, dA + 2048);
    gl2lds16(pB0 + k0, dB);
    gl2lds16(pB1 + k0, dB + 2048);
    __syncthreads();
    bf16x8 af[4], bfr[4];
#pragma unroll
    for (int i = 0; i < 4; i++) {
      af[i]  = *reinterpret_cast<const bf16x8*>(&As[(wm + i * 16 + l15) * 32 + quad * 8]);
      bfr[i] = *reinterpret_cast<const bf16x8*>(&Bs[(wn + i * 16 + l15) * 32 + quad * 8]);
    }
#pragma unroll
    for (int i = 0; i < 4; i++)
#pragma unroll
      for (int j = 0; j < 4; j++)
        acc[i][j] = __builtin_amdgcn_mfma_f32_16x16x32_bf16(af[i], bfr[j], acc[i][j], 0, 0, 0);
  }

  const float rs = 0.03857583749f;  // 1/sqrt(672)
#pragma unroll
  for (int i = 0; i < 4; i++) {
#pragma unroll
    for (int j = 0; j < 4; j++) {
      int col = n0 + wn + j * 16 + l15;
      if (col >= N) continue;
#pragma unroll
      for (int rr = 0; rr < 4; rr++) {
        int row = m0 + wm + i * 16 + quad * 4 + rr;
        if (row >= M) continue;
        float v = acc[i][j][rr];
        if (MODE == 1) v = (col <= row) ? v * rs * __expf(a1[col] - a2[row]) : 0.f;
        else if (MODE == 2) v = v * a1[row];
        if (OUTF32) C32[(long)row * ldc + col] = v;
        else        C16[(long)row * ldc + col] = f2b(v);
      }
    }
  }
}

// ---------------------------------------------------------------------------
__global__ __launch_bounds__(256) void transpose_any(
    const void* __restrict__ in, u16* __restrict__ out, int R, int C,
    long inStride, long outStride, const u16* __restrict__ sx, int dosniff)
{
  __shared__ u16 tile[64][65];
  bool f32 = dosniff && (sniff_f32(sx) != 0);
  long bz = blockIdx.z;
  const u16* in16 = (const u16*)in + bz * inStride;
  const float* inf = (const float*)in + bz * inStride;
  out += bz * outStride;
  int r0 = blockIdx.y * 64, c0 = blockIdx.x * 64;
  int t = threadIdx.x;
  for (int idx = t; idx < 64 * 64; idx += 256) {
    int r = idx >> 6, c = idx & 63;
    int rr = r0 + r, cc = c0 + c;
    u16 v = 0;
    if (rr < R && cc < C) {
      long off = (long)rr * C + cc;
      v = f32 ? f2b(inf[off]) : in16[off];
    }
    tile[r][c] = v;
  }
  __syncthreads();
  for (int idx = t; idx < 64 * 64; idx += 256) {
    int r = idx & 63, c = idx >> 6;
    int rr = r0 + r, cc = c0 + c;
    if (rr < R && cc < C) out[(long)cc * R + rr] = tile[r][c];
  }
}

// ---------------------------------------------------------------------------
__global__ __launch_bounds__(256) void convert_x(
    const void* __restrict__ x, u16* __restrict__ o, const u16* __restrict__ sx)
{
  int f = sniff_f32(sx);
  long i = ((long)blockIdx.x * 256 + threadIdx.x) * 4;
  if (i >= (long)4096 * EE) return;
  if (f) {
    float4 v = *reinterpret_cast<const float4*>((const float*)x + i);
    u16 t4[4] = {f2b(v.x), f2b(v.y), f2b(v.z), f2b(v.w)};
    *reinterpret_cast<uint2*>(o + i) = *reinterpret_cast<uint2*>(t4);
  } else {
    *reinterpret_cast<uint2*>(o + i) = *reinterpret_cast<const uint2*>((const u16*)x + i);
  }
}

// ---------------------------------------------------------------------------
__global__ __launch_bounds__(256) void conv_silu(
    const u16* __restrict__ xinner, const void* __restrict__ cw,
    const void* __restrict__ cb, u16* __restrict__ xca, const u16* __restrict__ sx)
{
  int f = sniff_f32(sx);
  long idx = (long)blockIdx.x * 256 + threadIdx.x;
  if (idx >= (long)BB * SS * HH) return;
  int h = (int)(idx % HH);
  long bs = idx / HH;
  int s = (int)(bs % SS);
  float acc = ldin(cb, h, f);
#pragma unroll
  for (int w = 0; w < 4; w++) {
    int ss = s + w - 3;
    if (ss >= 0) acc += b2f(xinner[(bs - s + ss) * H2 + h]) * ldin(cw, w * HH + h, f);
  }
  xca[idx] = f2b(silu_f(acc));
}

// ---------------------------------------------------------------------------
__global__ __launch_bounds__(256) void headwise_qkv(
    const u16* __restrict__ xinner, const u16* __restrict__ xca,
    const void* __restrict__ Wq, const void* __restrict__ Wk, const void* __restrict__ Wv,
    u16* __restrict__ q, u16* __restrict__ k, u16* __restrict__ v,
    const u16* __restrict__ sx)
{
  int f = sniff_f32(sx);
  int idx = blockIdx.x * 256 + threadIdx.x;
  if (idx >= BB * SS * NPHH) return;
  int nph = idx % NPHH;
  int bs = idx / NPHH;
  int cbase = nph * 4;
  float xa[4], xm[4];
  const u16* xcap = xca + (long)bs * HH + cbase;
  const u16* xmp  = xinner + (long)bs * H2 + cbase;
#pragma unroll
  for (int d = 0; d < 4; d++) { xa[d] = b2f(xcap[d]); xm[d] = b2f(xmp[d]); }
  int n = cbase / DHH;
  int d0 = cbase - n * DHH;
  long obase = (((long)(bs / SS) * NHH + n) * SS + (bs % SS)) * DHH + d0;
#pragma unroll
  for (int o = 0; o < 4; o++) {
    float aq = 0.f, ak = 0.f, av = 0.f;
#pragma unroll
    for (int d = 0; d < 4; d++) {
      aq += xa[d] * ldin(Wq, (nph * 4 + d) * 4 + o, f);
      ak += xa[d] * ldin(Wk, (nph * 4 + d) * 4 + o, f);
      av += xm[d] * ldin(Wv, (nph * 4 + d) * 4 + o, f);
    }
    q[obase + o] = f2b(aq);
    k[obase + o] = f2b(ak);
    v[obase + o] = f2b(av);
  }
}

// ---------------------------------------------------------------------------
__global__ __launch_bounds__(256) void gates_kernel(
    const u16* __restrict__ q, const u16* __restrict__ k, const u16* __restrict__ v,
    const void* __restrict__ Wig, const void* __restrict__ big,
    const void* __restrict__ Wfg, const void* __restrict__ bfg,
    float* __restrict__ ipre, float* __restrict__ fpre, const u16* __restrict__ sx)
{
  int f = sniff_f32(sx);
  int wave = (blockIdx.x * 256 + threadIdx.x) >> 6;
  int lane = threadIdx.x & 63;
  if (wave >= BB * SS) return;
  int b = wave / SS, s = wave % SS;
  float ai[4] = {0,0,0,0}, af[4] = {0,0,0,0};
  for (int c = lane; c < HH; c += 64) {
    int n = c / DHH, d = c % DHH;
    long qi = (((long)b * NHH + n) * SS + s) * DHH + d;
    float qv = b2f(q[qi]), kv = b2f(k[qi]), vv = b2f(v[qi]);
#pragma unroll
    for (int nn = 0; nn < 4; nn++) {
      ai[nn] += qv * ldin(Wig, c * 4 + nn, f) + kv * ldin(Wig, (HH + c) * 4 + nn, f) +
                vv * ldin(Wig, (2 * HH + c) * 4 + nn, f);
      af[nn] += qv * ldin(Wfg, c * 4 + nn, f) + kv * ldin(Wfg, (HH + c) * 4 + nn, f) +
                vv * ldin(Wfg, (2 * HH + c) * 4 + nn, f);
    }
  }
#pragma unroll
  for (int off = 32; off > 0; off >>= 1) {
#pragma unroll
    for (int nn = 0; nn < 4; nn++) {
      ai[nn] += __shfl_down(ai[nn], off);
      af[nn] += __shfl_down(af[nn], off);
    }
  }
  if (lane == 0) {
#pragma unroll
    for (int nn = 0; nn < 4; nn++) {
      ipre[((long)b * NHH + nn) * SS + s] = ai[nn] + ldin(big, nn, f);
      fpre[((long)b * NHH + nn) * SS + s] = af[nn] + ldin(bfg, nn, f);
    }
  }
}

// ---------------------------------------------------------------------------
__global__ __launch_bounds__(1024) void scan_kernel(
    const float* __restrict__ ipre, const float* __restrict__ fpre,
    float* __restrict__ avec, float* __restrict__ rmaxvec, float* __restrict__ mvec)
{
  __shared__ float buf[2][SS];
  __shared__ float cssave[SS];
  int bn = blockIdx.x;
  const float* fp = fpre + (long)bn * SS;
  const float* ip = ipre + (long)bn * SS;
  int t = threadIdx.x;
  for (int i = t; i < SS; i += 1024) buf[0][i] = logsig_f(fp[i]);
  __syncthreads();
  int src = 0;
  for (int off = 1; off < SS; off <<= 1) {
    int dst = 1 - src;
    for (int i = t; i < SS; i += 1024) {
      float x = buf[src][i];
      if (i >= off) x += buf[src][i - off];
      buf[dst][i] = x;
    }
    __syncthreads();
    src = dst;
  }
  for (int i = t; i < SS; i += 1024) {
    float cs = buf[src][i];
    cssave[i] = cs;
    float a = ip[i] - cs;
    avec[(long)bn * SS + i] = a;
    buf[src][i] = a;
  }
  __syncthreads();
  for (int off = 1; off < SS; off <<= 1) {
    int dst = 1 - src;
    for (int i = t; i < SS; i += 1024) {
      float x = buf[src][i];
      if (i >= off) x = fmaxf(x, buf[src][i - off]);
      buf[dst][i] = x;
    }
    __syncthreads();
    src = dst;
  }
  for (int i = t; i < SS; i += 1024) {
    rmaxvec[(long)bn * SS + i] = buf[src][i];
    mvec[(long)bn * SS + i] = cssave[i] + buf[src][i];
  }
}

// ---------------------------------------------------------------------------
// causal row sums (j<=row only; upper-tri P is never written)
__global__ __launch_bounds__(256) void rowsum_kernel(
    const u16* __restrict__ P, const float* __restrict__ mvec, float* __restrict__ invn,
    long Pstride)
{
  int bz = blockIdx.z;
  P += (long)bz * Pstride;
  mvec += (long)bz * SS;
  invn += (long)bz * SS;
  int row = (blockIdx.x * 256 + threadIdx.x) >> 6;
  int lane = threadIdx.x & 63;
  if (row >= SS) return;
  const u16* pr = P + (long)row * SS;
  float s = 0.f;
  for (int j = lane; j <= row; j += 64) s += b2f(pr[j]);
#pragma unroll
  for (int off = 32; off > 0; off >>= 1) s += __shfl_down(s, off);
  if (lane == 0) {
    float n = fmaxf(fabsf(s), __expf(-mvec[row]));
    invn[row] = 1.f / (n + 1e-6f);
  }
}

// ---------------------------------------------------------------------------
__global__ __launch_bounds__(256) void ln_skip_gate(
    const u16* __restrict__ h, const u16* __restrict__ xca,
    const u16* __restrict__ xinner, const void* __restrict__ normw,
    const void* __restrict__ skipw, u16* __restrict__ hs, const u16* __restrict__ sx)
{
  int f = sniff_f32(sx);
  int row = (blockIdx.x * 256 + threadIdx.x) >> 6;
  int lane = threadIdx.x & 63;
  if (row >= BB * NHH * SS) return;
  int s = row % SS;
  int n = (row / SS) % NHH;
  int b = row / (SS * NHH);
  const u16* hr = h + (long)row * DHH;
  float sum = 0.f, ss = 0.f;
  float vals[11];
  int cnt = 0;
  for (int d = lane; d < DHH; d += 64) {
    float x = b2f(hr[d]);
    vals[cnt++] = x; sum += x; ss += x * x;
  }
#pragma unroll
  for (int off = 32; off > 0; off >>= 1) { sum += __shfl_down(sum, off); ss += __shfl_down(ss, off); }
  sum = __shfl(sum, 0); ss = __shfl(ss, 0);
  float mu = sum / (float)DHH;
  float var = ss / (float)DHH - mu * mu;
  float rstd = rsqrtf(var + 1e-5f);
  long bs = (long)b * SS + s;
  cnt = 0;
  for (int d = lane; d < DHH; d += 64) {
    int c = n * DHH + d;
    float hn = (vals[cnt++] - mu) * rstd * ldin(normw, c, f);
    float hskip = hn + ldin(skipw, c, f) * b2f(xca[bs * HH + c]);
    float z = b2f(xinner[bs * H2 + HH + c]);
    hs[bs * HH + c] = f2b(hskip * silu_f(z));
  }
}

// ---------------------------------------------------------------------------
__global__ __launch_bounds__(256) void fill_sentinel(float* out, float v, long n) {
  long i = (long)blockIdx.x * 256 + threadIdx.x;
  if (i < n) out[i] = v;
}

// ---------------------------------------------------------------------------
extern "C" void kernel_launch(void* const* d_in, const int* in_sizes, int n_in,
                              void* d_out, int out_size, void* d_ws, size_t ws_size,
                              hipStream_t stream)
{
  const u16* sx      = (const u16*)d_in[0];
  const void* x      = d_in[0];
  const void* W_in   = d_in[1];
  const void* conv_w = d_in[2];
  const void* conv_b = d_in[3];
  const void* Wq     = d_in[4];
  const void* Wk     = d_in[5];
  const void* Wv     = d_in[6];
  const void* W_ig   = d_in[7];
  const void* b_ig   = d_in[8];
  const void* W_fg   = d_in[9];
  const void* b_fg   = d_in[10];
  const void* norm_w = d_in[11];
  const void* skipw  = d_in[12];
  const void* W_out  = d_in[13];
  float* out = (float*)d_out;
  const long SD = (long)SS * DHH;
  const long SP = (long)SS * SS;

  u16* ws = (u16*)d_ws;
  size_t off = 0;
  auto alloc = [&](size_t n) { u16* p = ws + off; off += n; return p; };
  u16* x_inner = alloc((size_t)4096 * H2);     // 22,020,096
  u16* xca     = alloc((size_t)4096 * HH);     // 11,010,048
  u16* qb      = alloc((size_t)8 * SD);        // W_inT -> q -> hs
  u16* kb      = alloc((size_t)8 * SD);        // xbf -> k -> h
  u16* vb      = alloc((size_t)8 * SD);        // v -> W_outT
  float* fb = (float*)(ws + off);
  off += 6 * 16384 * 2;                        // 6 fp32 vectors (as u16 elems)
  float* ipre    = fb;
  float* fpre    = ipre + 16384;
  float* avec    = fpre + 16384;
  float* rmaxvec = avec + 16384;
  float* mvec    = rmaxvec + 16384;
  float* invn    = mvec + 16384;
  u16* vt8 = alloc((size_t)8 * SD);            // batched v^T
  size_t need_fb_base = (off - 8 * SD + SD) * 2;  // fallback uses 1 vt slice
  u16* Pb8 = alloc((size_t)8 * SP);            // batched P
  size_t need_batched = off * 2;
  size_t need_fallback = need_fb_base + SP * 2;
  long outn = (long)4096 * EE;

  if (ws_size < need_fallback) {
    fill_sentinel<<<dim3((outn + 255) / 256), 256, 0, stream>>>(
        out, 200.f + 0.01f * (float)(ws_size >> 20), outn);
    return;
  }
  bool batched = (ws_size >= need_batched);

  u16* W_inT  = qb;
  u16* xbf    = kb;
  u16* W_outT = vb;
  u16* hbuf   = kb;
  u16* hsbuf  = qb;

  transpose_any<<<dim3(84, 32, 1), 256, 0, stream>>>(W_in, W_inT, EE, H2, 0, 0, sx, 1);
  convert_x<<<dim3(8192, 1, 1), 256, 0, stream>>>(x, xbf, sx);
  gemm_nt<0, 0><<<dim3(42, 32, 1), 256, 0, stream>>>(
      xbf, W_inT, x_inner, 4096, H2, EE, EE, EE, H2, 0, 0, 0, nullptr, nullptr, 0, 0);
  conv_silu<<<dim3(43008, 1, 1), 256, 0, stream>>>(x_inner, conv_w, conv_b, xca, sx);
  headwise_qkv<<<dim3(10752, 1, 1), 256, 0, stream>>>(
      x_inner, xca, Wq, Wk, Wv, qb, kb, vb, sx);
  gates_kernel<<<dim3(1024, 1, 1), 256, 0, stream>>>(
      qb, kb, vb, W_ig, b_ig, W_fg, b_fg, ipre, fpre, sx);
  scan_kernel<<<dim3(8, 1, 1), 1024, 0, stream>>>(ipre, fpre, avec, rmaxvec, mvec);

  if (batched) {
    transpose_any<<<dim3(11, 32, 8), 256, 0, stream>>>(vb, vt8, SS, DHH, SD, SD, nullptr, 0);
    gemm_nt<1, 0><<<dim3(16, 16, 8), 256, 0, stream>>>(
        qb, kb, Pb8, SS, SS, DHH, DHH, DHH, SS, SD, SD, SP, avec, rmaxvec, SS, 0);
    rowsum_kernel<<<dim3(512, 1, 8), 256, 0, stream>>>(Pb8, mvec, invn, SP);
    gemm_nt<2, 0><<<dim3(6, 16, 8), 256, 0, stream>>>(
        Pb8, vt8, hbuf, SS, DHH, SS, SS, SS, DHH, SP, SD, SD, invn, nullptr, SS, 1);
  } else {
    for (int bn = 0; bn < 8; bn++) {
      transpose_any<<<dim3(11, 32, 1), 256, 0, stream>>>(
          vb + bn * SD, vt8, SS, DHH, 0, 0, nullptr, 0);
      gemm_nt<1, 0><<<dim3(16, 16, 1), 256, 0, stream>>>(
          qb + bn * SD, kb + bn * SD, Pb8, SS, SS, DHH, DHH, DHH, SS, 0, 0, 0,
          avec + bn * SS, rmaxvec + bn * SS, 0, 0);
      rowsum_kernel<<<dim3(512, 1, 1), 256, 0, stream>>>(
          Pb8, mvec + bn * SS, invn + bn * SS, 0);
      gemm_nt<2, 0><<<dim3(6, 16, 1), 256, 0, stream>>>(
          Pb8, vt8, hbuf + bn * SD, SS, DHH, SS, SS, SS, DHH, 0, 0, 0,
          invn + bn * SS, nullptr, 0, 1);
    }
  }

  transpose_any<<<dim3(32, 42, 1), 256, 0, stream>>>(W_out, W_outT, HH, EE, 0, 0, sx, 1);
  ln_skip_gate<<<dim3(4096, 1, 1), 256, 0, stream>>>(
      hbuf, xca, x_inner, norm_w, skipw, hsbuf, sx);
  gemm_nt<0, 1><<<dim3(16, 32, 1), 256, 0, stream>>>(
      hsbuf, W_outT, out, 4096, EE, HH, HH, HH, EE, 0, 0, 0, nullptr, nullptr, 0, 0);
}

// Round 6
// 740.087 us; speedup vs baseline: 3.2464x; 1.6643x over previous
//
#include <hip/hip_runtime.h>

typedef unsigned short u16;
typedef unsigned int u32;
typedef __bf16 bf16x8 __attribute__((ext_vector_type(8)));
typedef float f32x4 __attribute__((ext_vector_type(4)));

#define BB   2
#define SS   2048
#define EE   2048
#define HH   2688
#define NHH  4
#define DHH  672
#define NPHH 672
#define H2   5376
#define H3   8064

__device__ __forceinline__ float b2f(u16 u) {
  union { unsigned int i; float f; } c; c.i = ((unsigned int)u) << 16; return c.f;
}
__device__ __forceinline__ u16 f2b(float f) {
  union { float f; unsigned int i; } c; c.f = f;
  unsigned int i = c.i;
  return (u16)((i + 0x7FFFu + ((i >> 16) & 1u)) >> 16);
}
__device__ __forceinline__ float silu_f(float x) { return x / (1.f + __expf(-x)); }
__device__ __forceinline__ float logsig_f(float f) {
  return (f >= 0.f) ? -log1pf(__expf(-f)) : (f - log1pf(__expf(f)));
}

// async global->LDS, 16B per lane; dst wave-uniform base, HW adds lane*16B
__device__ __forceinline__ void gl2lds16(const u16* g, u16* s) {
  __builtin_amdgcn_global_load_lds(
      (const __attribute__((address_space(1))) u32*)g,
      (__attribute__((address_space(3))) u32*)s, 16, 0, 0);
}

// ---------------------------------------------------------------------------
// NT GEMM (bf16): C[i,j] = sum_k A[i,k]*Bt[j,k]
// MODE 0 plain; MODE 1 QK epilogue (skip above-diag blocks);
// MODE 2 PV epilogue (row scale, causal K-cap). OUTF32: fp32 store.
// Batch offsets: bz decomposed as (bz>>2, bz&3) with hi/lo strides, so head
// slices of (B,S,H) tensors (base b*S*H + n*DH) batch without relayout.
// ---------------------------------------------------------------------------
template <int MODE, int OUTF32>
__global__ __launch_bounds__(256) void gemm_nt(
    const u16* __restrict__ A, const u16* __restrict__ Bt, void* __restrict__ Cp,
    int M, int N, int K, int lda, int ldb, int ldc,
    long sAhi, long sAlo, long sBhi, long sBlo, long sChi, long sClo,
    const float* __restrict__ aux1, const float* __restrict__ aux2,
    int auxStride, int causal)
{
  __shared__ __align__(16) u16 As[128 * 32];
  __shared__ __align__(16) u16 Bs[128 * 32];
  int m0 = blockIdx.y * 128, n0 = blockIdx.x * 128;
  if (MODE == 1 && n0 > m0 + 127) return;
  int bz = blockIdx.z, bzh = bz >> 2, bzl = bz & 3;
  A  += bzh * sAhi + bzl * sAlo;
  Bt += bzh * sBhi + bzl * sBlo;
  const float* a1 = aux1 ? aux1 + (long)bz * auxStride : nullptr;
  const float* a2 = aux2 ? aux2 + (long)bz * auxStride : nullptr;
  u16*   C16 = (u16*)Cp + bzh * sChi + bzl * sClo;
  float* C32 = (float*)Cp + bzh * sChi + bzl * sClo;

  int t = threadIdx.x, lane = t & 63, wid = t >> 6;
  int wm = (wid >> 1) * 64, wn = (wid & 1) * 64;
  int l15 = lane & 15, quad = lane >> 4;

  int srow = wid * 16 + (lane >> 2);
  int scol = (lane & 3) * 8;
  const u16* pA0 = A + (long)(m0 + srow) * lda + scol;
  const u16* pA1 = pA0 + (long)64 * lda;
  const u16* pB0 = Bt + (long)(n0 + srow) * ldb + scol;
  const u16* pB1 = pB0 + (long)64 * ldb;
  u16* dA = As + wid * 512;
  u16* dB = Bs + wid * 512;

  f32x4 acc[4][4];
#pragma unroll
  for (int i = 0; i < 4; i++)
#pragma unroll
    for (int j = 0; j < 4; j++) acc[i][j] = (f32x4){0.f, 0.f, 0.f, 0.f};

  int Keff = (MODE == 2 && causal) ? min(K, m0 + 128) : K;

  for (int k0 = 0; k0 < Keff; k0 += 32) {
    __syncthreads();
    gl2lds16(pA0 + k0, dA);
    gl2lds16(pA1 + k0, dA + 2048);
    gl2lds16(pB0 + k0, dB);
    gl2lds16(pB1 + k0, dB + 2048);
    __syncthreads();
    bf16x8 af[4], bfr[4];
#pragma unroll
    for (int i = 0; i < 4; i++) {
      af[i]  = *reinterpret_cast<const bf16x8*>(&As[(wm + i * 16 + l15) * 32 + quad * 8]);
      bfr[i] = *reinterpret_cast<const bf16x8*>(&Bs[(wn + i * 16 + l15) * 32 + quad * 8]);
    }
#pragma unroll
    for (int i = 0; i < 4; i++)
#pragma unroll
      for (int j = 0; j < 4; j++)
        acc[i][j] = __builtin_amdgcn_mfma_f32_16x16x32_bf16(af[i], bfr[j], acc[i][j], 0, 0, 0);
  }

  const float rs = 0.03857583749f;  // 1/sqrt(672)
#pragma unroll
  for (int i = 0; i < 4; i++) {
#pragma unroll
    for (int j = 0; j < 4; j++) {
      int col = n0 + wn + j * 16 + l15;
      if (col >= N) continue;
#pragma unroll
      for (int rr = 0; rr < 4; rr++) {
        int row = m0 + wm + i * 16 + quad * 4 + rr;
        if (row >= M) continue;
        float v = acc[i][j][rr];
        if (MODE == 1) v = (col <= row) ? v * rs * __expf(a1[col] - a2[row]) : 0.f;
        else if (MODE == 2) v = v * a1[row];
        if (OUTF32) C32[(long)row * ldc + col] = v;
        else        C16[(long)row * ldc + col] = f2b(v);
      }
    }
  }
}

// ---------------------------------------------------------------------------
// transpose with row stride: out[c*R + r] = in[r*ldin + c]; F32IN: fp32 source
// ---------------------------------------------------------------------------
template <int F32IN>
__global__ __launch_bounds__(256) void transpose_any(
    const void* __restrict__ in, u16* __restrict__ out, int R, int C, int ldin,
    long inHi, long inLo, long outStride)
{
  __shared__ u16 tile[64][65];
  int bz = blockIdx.z, bzh = bz >> 2, bzl = bz & 3;
  const u16* in16 = (const u16*)in + bzh * inHi + bzl * inLo;
  const float* inf = (const float*)in + bzh * inHi + bzl * inLo;
  out += (long)bz * outStride;
  int r0 = blockIdx.y * 64, c0 = blockIdx.x * 64;
  int t = threadIdx.x;
  for (int idx = t; idx < 64 * 64; idx += 256) {
    int r = idx >> 6, c = idx & 63;
    int rr = r0 + r, cc = c0 + c;
    u16 v = 0;
    if (rr < R && cc < C) {
      long off = (long)rr * ldin + cc;
      v = F32IN ? f2b(inf[off]) : in16[off];
    }
    tile[r][c] = v;
  }
  __syncthreads();
  for (int idx = t; idx < 64 * 64; idx += 256) {
    int r = idx & 63, c = idx >> 6;
    int rr = r0 + r, cc = c0 + c;
    if (rr < R && cc < C) out[(long)cc * R + rr] = tile[r][c];
  }
}

// ---------------------------------------------------------------------------
// x fp32 -> bf16, 8/thread
__global__ __launch_bounds__(256) void convert_x(
    const float* __restrict__ x, u16* __restrict__ o)
{
  long i = ((long)blockIdx.x * 256 + threadIdx.x) * 8;
  if (i >= (long)4096 * EE) return;
  float4 a = *reinterpret_cast<const float4*>(x + i);
  float4 b = *reinterpret_cast<const float4*>(x + i + 4);
  u16 t8[8] = {f2b(a.x), f2b(a.y), f2b(a.z), f2b(a.w),
               f2b(b.x), f2b(b.y), f2b(b.z), f2b(b.w)};
  *reinterpret_cast<uint4*>(o + i) = *reinterpret_cast<uint4*>(t8);
}

// ---------------------------------------------------------------------------
// WT3 (128 x 2688 bf16): rows r<24: r=seg*8+j -> (j<4?W_ig:W_fg)[seg*H + c, j&3]
__global__ __launch_bounds__(256) void prep_wt3(
    const float* __restrict__ Wig, const float* __restrict__ Wfg,
    u16* __restrict__ WT3)
{
  int i = blockIdx.x * 256 + threadIdx.x;
  if (i >= 128 * HH) return;
  int r = i / HH, c = i % HH;
  float v = 0.f;
  if (r < 24) {
    int seg = r >> 3, j = r & 7;
    const float* W = (j < 4) ? Wig : Wfg;
    v = W[(long)(seg * HH + c) * 4 + (j & 3)];
  }
  WT3[i] = f2b(v);
}

// Wq|Wk|Wv fp32 -> bf16 packed (3 x 10752)
__global__ __launch_bounds__(256) void prep_wqkv(
    const float* __restrict__ Wq, const float* __restrict__ Wk,
    const float* __restrict__ Wv, u16* __restrict__ o)
{
  int i = blockIdx.x * 256 + threadIdx.x;
  if (i >= 3 * 10752) return;
  int m = i / 10752, j = i % 10752;
  const float* W = (m == 0) ? Wq : (m == 1) ? Wk : Wv;
  o[i] = f2b(W[j]);
}

// ---------------------------------------------------------------------------
// depthwise causal conv (KS=4) + bias + silu, 4 h/thread
__global__ __launch_bounds__(256) void conv_silu(
    const u16* __restrict__ xinner, const float* __restrict__ cw,
    const float* __restrict__ cb, u16* __restrict__ xca)
{
  long idx = (long)blockIdx.x * 256 + threadIdx.x;
  if (idx >= (long)BB * SS * HH / 4) return;
  int h4 = (int)(idx % (HH / 4)) * 4;
  long bs = idx / (HH / 4);
  int s = (int)(bs % SS);
  float4 acc = *reinterpret_cast<const float4*>(cb + h4);
#pragma unroll
  for (int w = 0; w < 4; w++) {
    int sp = s + w - 3;
    if (sp < 0) continue;
    uint2 xr = *reinterpret_cast<const uint2*>(xinner + (bs + w - 3) * H2 + h4);
    const u16* xh = (const u16*)&xr;
    float4 cwv = *reinterpret_cast<const float4*>(cw + w * HH + h4);
    acc.x += b2f(xh[0]) * cwv.x;
    acc.y += b2f(xh[1]) * cwv.y;
    acc.z += b2f(xh[2]) * cwv.z;
    acc.w += b2f(xh[3]) * cwv.w;
  }
  u16 o4[4] = {f2b(silu_f(acc.x)), f2b(silu_f(acc.y)),
               f2b(silu_f(acc.z)), f2b(silu_f(acc.w))};
  *reinterpret_cast<uint2*>(xca + bs * HH + h4) = *reinterpret_cast<uint2*>(o4);
}

// ---------------------------------------------------------------------------
// headwise 4x4 projections, outputs stay in (B,S,H) layout (no relayout)
__global__ __launch_bounds__(256) void headwise_qkv(
    const u16* __restrict__ xinner, const u16* __restrict__ xca,
    const u16* __restrict__ Wqkv,
    u16* __restrict__ q, u16* __restrict__ k, u16* __restrict__ v)
{
  int idx = blockIdx.x * 256 + threadIdx.x;
  if (idx >= BB * SS * NPHH) return;
  int nph = idx % NPHH;
  long bs = idx / NPHH;
  int cbase = nph * 4;
  uint2 xar = *reinterpret_cast<const uint2*>(xca + bs * HH + cbase);
  uint2 xmr = *reinterpret_cast<const uint2*>(xinner + bs * H2 + cbase);
  const u16* xa = (const u16*)&xar;
  const u16* xm = (const u16*)&xmr;
  float xaf[4], xmf[4];
#pragma unroll
  for (int d = 0; d < 4; d++) { xaf[d] = b2f(xa[d]); xmf[d] = b2f(xm[d]); }
  union { uint4 v4[2]; u16 h[16]; } wq, wk, wv;
  const uint4* wqp = reinterpret_cast<const uint4*>(Wqkv + nph * 16);
  const uint4* wkp = reinterpret_cast<const uint4*>(Wqkv + 10752 + nph * 16);
  const uint4* wvp = reinterpret_cast<const uint4*>(Wqkv + 21504 + nph * 16);
  wq.v4[0] = wqp[0]; wq.v4[1] = wqp[1];
  wk.v4[0] = wkp[0]; wk.v4[1] = wkp[1];
  wv.v4[0] = wvp[0]; wv.v4[1] = wvp[1];
  u16 qo[4], ko[4], vo[4];
#pragma unroll
  for (int o = 0; o < 4; o++) {
    float aq = 0.f, ak = 0.f, av = 0.f;
#pragma unroll
    for (int d = 0; d < 4; d++) {
      aq += xaf[d] * b2f(wq.h[d * 4 + o]);
      ak += xaf[d] * b2f(wk.h[d * 4 + o]);
      av += xmf[d] * b2f(wv.h[d * 4 + o]);
    }
    qo[o] = f2b(aq); ko[o] = f2b(ak); vo[o] = f2b(av);
  }
  long ob = bs * HH + cbase;
  *reinterpret_cast<uint2*>(q + ob) = *reinterpret_cast<uint2*>(qo);
  *reinterpret_cast<uint2*>(k + ob) = *reinterpret_cast<uint2*>(ko);
  *reinterpret_cast<uint2*>(v + ob) = *reinterpret_cast<uint2*>(vo);
}

// ---------------------------------------------------------------------------
// per (b,n): ipre/fpre from G (12288x24) + bias; cs=cumsum(logsig(f));
// a=i-cs; rmax=prefmax(a); m=cs+rmax
__global__ __launch_bounds__(1024) void scan_kernel(
    const float* __restrict__ G, const float* __restrict__ big,
    const float* __restrict__ bfg,
    float* __restrict__ avec, float* __restrict__ rmaxvec, float* __restrict__ mvec)
{
  __shared__ float buf[2][SS];
  __shared__ float isave[SS];
  __shared__ float cssave[SS];
  int bn = blockIdx.x;
  int b = bn >> 2, n = bn & 3;
  int t = threadIdx.x;
  float bi = big[n], bf = bfg[n];
  for (int i = t; i < SS; i += 1024) {
    long tk = (long)b * SS + i;
    float ip = G[tk * 24 + n] + G[(4096 + tk) * 24 + 8 + n] +
               G[(8192 + tk) * 24 + 16 + n] + bi;
    float fp = G[tk * 24 + 4 + n] + G[(4096 + tk) * 24 + 12 + n] +
               G[(8192 + tk) * 24 + 20 + n] + bf;
    isave[i] = ip;
    buf[0][i] = logsig_f(fp);
  }
  __syncthreads();
  int src = 0;
  for (int off = 1; off < SS; off <<= 1) {
    int dst = 1 - src;
    for (int i = t; i < SS; i += 1024) {
      float x = buf[src][i];
      if (i >= off) x += buf[src][i - off];
      buf[dst][i] = x;
    }
    __syncthreads();
    src = dst;
  }
  for (int i = t; i < SS; i += 1024) {
    float cs = buf[src][i];
    cssave[i] = cs;
    float a = isave[i] - cs;
    avec[(long)bn * SS + i] = a;
    buf[src][i] = a;
  }
  __syncthreads();
  for (int off = 1; off < SS; off <<= 1) {
    int dst = 1 - src;
    for (int i = t; i < SS; i += 1024) {
      float x = buf[src][i];
      if (i >= off) x = fmaxf(x, buf[src][i - off]);
      buf[dst][i] = x;
    }
    __syncthreads();
    src = dst;
  }
  for (int i = t; i < SS; i += 1024) {
    rmaxvec[(long)bn * SS + i] = buf[src][i];
    mvec[(long)bn * SS + i] = cssave[i] + buf[src][i];
  }
}

// ---------------------------------------------------------------------------
// causal row sums of P -> inv_n
__global__ __launch_bounds__(256) void rowsum_kernel(
    const u16* __restrict__ P, const float* __restrict__ mvec, float* __restrict__ invn,
    long Pstride)
{
  int bz = blockIdx.z;
  P += (long)bz * Pstride;
  mvec += (long)bz * SS;
  invn += (long)bz * SS;
  int row = (blockIdx.x * 256 + threadIdx.x) >> 6;
  int lane = threadIdx.x & 63;
  if (row >= SS) return;
  const u16* pr = P + (long)row * SS;
  float s = 0.f;
  for (int j = lane; j <= row; j += 64) s += b2f(pr[j]);
#pragma unroll
  for (int off = 32; off > 0; off >>= 1) s += __shfl_down(s, off);
  if (lane == 0) {
    float n = fmaxf(fabsf(s), __expf(-mvec[row]));
    invn[row] = 1.f / (n + 1e-6f);
  }
}

// ---------------------------------------------------------------------------
__global__ __launch_bounds__(256) void ln_skip_gate(
    const u16* __restrict__ h, const u16* __restrict__ xca,
    const u16* __restrict__ xinner, const float* __restrict__ normw,
    const float* __restrict__ skipw, u16* __restrict__ hs)
{
  int row = (blockIdx.x * 256 + threadIdx.x) >> 6;  // (b*NH+n)*S + s
  int lane = threadIdx.x & 63;
  if (row >= BB * NHH * SS) return;
  int s = row % SS;
  int n = (row / SS) % NHH;
  int b = row / (SS * NHH);
  const u16* hr = h + (long)row * DHH;
  float sum = 0.f, ss = 0.f;
  float vals[11];
  int cnt = 0;
  for (int d = lane; d < DHH; d += 64) {
    float x = b2f(hr[d]);
    vals[cnt++] = x; sum += x; ss += x * x;
  }
#pragma unroll
  for (int off = 32; off > 0; off >>= 1) { sum += __shfl_down(sum, off); ss += __shfl_down(ss, off); }
  sum = __shfl(sum, 0); ss = __shfl(ss, 0);
  float mu = sum / (float)DHH;
  float var = ss / (float)DHH - mu * mu;
  float rstd = rsqrtf(var + 1e-5f);
  long bs = (long)b * SS + s;
  cnt = 0;
  for (int d = lane; d < DHH; d += 64) {
    int c = n * DHH + d;
    float hn = (vals[cnt++] - mu) * rstd * normw[c];
    float hskip = hn + skipw[c] * b2f(xca[bs * HH + c]);
    float z = b2f(xinner[bs * H2 + HH + c]);
    hs[bs * HH + c] = f2b(hskip * silu_f(z));
  }
}

// ---------------------------------------------------------------------------
__global__ __launch_bounds__(256) void fill_sentinel(float* out, float v, long n) {
  long i = (long)blockIdx.x * 256 + threadIdx.x;
  if (i < n) out[i] = v;
}

// ---------------------------------------------------------------------------
extern "C" void kernel_launch(void* const* d_in, const int* in_sizes, int n_in,
                              void* d_out, int out_size, void* d_ws, size_t ws_size,
                              hipStream_t stream)
{
  const float* x      = (const float*)d_in[0];
  const float* W_in   = (const float*)d_in[1];
  const float* conv_w = (const float*)d_in[2];
  const float* conv_b = (const float*)d_in[3];
  const float* Wq     = (const float*)d_in[4];
  const float* Wk     = (const float*)d_in[5];
  const float* Wv     = (const float*)d_in[6];
  const float* W_ig   = (const float*)d_in[7];
  const float* b_ig   = (const float*)d_in[8];
  const float* W_fg   = (const float*)d_in[9];
  const float* b_fg   = (const float*)d_in[10];
  const float* norm_w = (const float*)d_in[11];
  const float* skipw  = (const float*)d_in[12];
  const float* W_out  = (const float*)d_in[13];
  float* out = (float*)d_out;
  const long SD = (long)SS * DHH;     // head slice elems
  const long SP = (long)SS * SS;
  const long BH = (long)SS * HH;      // per-batch elems of (S,H)

  u16* ws = (u16*)d_ws;
  size_t off = 0;
  auto alloc = [&](size_t n) { u16* p = ws + off; off += n; return p; };
  u16* x_inner = alloc((size_t)4096 * H2);
  u16* xca     = alloc((size_t)4096 * HH);
  u16* qb      = alloc((size_t)4096 * HH);   // W_inT -> q -> hs
  u16* kb      = alloc((size_t)4096 * HH);   // xbf -> k -> h
  u16* vb      = alloc((size_t)4096 * HH);   // v -> W_outT
  float* fvec  = (float*)(ws + off);
  off += 4 * 16384 * 2;
  float* avec    = fvec;
  float* rmaxvec = avec + 16384;
  float* mvec    = rmaxvec + 16384;
  float* invn    = mvec + 16384;
  u16* vt8 = alloc((size_t)8 * SD);
  u16* Pb8 = alloc((size_t)8 * SP);
  size_t need = off * 2;
  long outn = (long)4096 * EE;

  if (ws_size < need) {
    fill_sentinel<<<dim3((outn + 255) / 256), 256, 0, stream>>>(
        out, 200.f + 0.01f * (float)(ws_size >> 20), outn);
    return;
  }

  // overlays
  u16* W_inT  = qb;                       // consumed before headwise writes q
  u16* xbf    = kb;                       // consumed before headwise writes k
  u16* W_outT = vb;                       // written after v's last use
  u16* hbuf   = kb;                       // h (bn,S,DH) after k's last use
  u16* hsbuf  = qb;                       // hs after q's last use
  u16* WT3    = Pb8;                      // 128x2688, consumed before QK
  float* G    = (float*)(Pb8 + 344064);   // 12288x24 fp32, consumed before QK
  u16* Wqkv   = Pb8 + 933888;             // 3x10752, consumed before QK

  prep_wt3<<<dim3(1344, 1, 1), 256, 0, stream>>>(W_ig, W_fg, WT3);
  prep_wqkv<<<dim3(126, 1, 1), 256, 0, stream>>>(Wq, Wk, Wv, Wqkv);
  transpose_any<1><<<dim3(84, 32, 1), 256, 0, stream>>>(
      W_in, W_inT, EE, H2, H2, 0, 0, 0);
  convert_x<<<dim3(4096, 1, 1), 256, 0, stream>>>(x, xbf);
  gemm_nt<0, 0><<<dim3(42, 32, 1), 256, 0, stream>>>(
      xbf, W_inT, x_inner, 4096, H2, EE, EE, EE, H2,
      0, 0, 0, 0, 0, 0, nullptr, nullptr, 0, 0);
  conv_silu<<<dim3(10752, 1, 1), 256, 0, stream>>>(x_inner, conv_w, conv_b, xca);
  headwise_qkv<<<dim3(10752, 1, 1), 256, 0, stream>>>(
      x_inner, xca, Wqkv, qb, kb, vb);
  // gates: [q;k;v] (12288 x 2688) @ WT3^T -> G (12288 x 24)
  gemm_nt<0, 1><<<dim3(1, 96, 1), 256, 0, stream>>>(
      qb, WT3, G, 12288, 24, HH, HH, HH, 24,
      0, 0, 0, 0, 0, 0, nullptr, nullptr, 0, 0);
  scan_kernel<<<dim3(8, 1, 1), 1024, 0, stream>>>(G, b_ig, b_fg, avec, rmaxvec, mvec);
  // v^T per (b,n): (DH, S)
  transpose_any<0><<<dim3(11, 32, 8), 256, 0, stream>>>(
      vb, vt8, SS, DHH, HH, BH, DHH, SD);
  // P = (q k^T / sqrt(DH)) * exp(a[col]-rmax[row]), causal
  gemm_nt<1, 0><<<dim3(16, 16, 8), 256, 0, stream>>>(
      qb, kb, Pb8, SS, SS, DHH, HH, HH, SS,
      BH, DHH, BH, DHH, 4 * SP, SP, avec, rmaxvec, SS, 0);
  rowsum_kernel<<<dim3(512, 1, 8), 256, 0, stream>>>(Pb8, mvec, invn, SP);
  // h = (P @ v) * inv_n, into (bn, S, DH)
  gemm_nt<2, 0><<<dim3(6, 16, 8), 256, 0, stream>>>(
      Pb8, vt8, hbuf, SS, DHH, SS, SS, SS, DHH,
      4 * SP, SP, 4 * SD, SD, 4 * SD, SD, invn, nullptr, SS, 1);
  transpose_any<1><<<dim3(32, 42, 1), 256, 0, stream>>>(
      W_out, W_outT, HH, EE, EE, 0, 0, 0);
  ln_skip_gate<<<dim3(4096, 1, 1), 256, 0, stream>>>(
      hbuf, xca, x_inner, norm_w, skipw, hsbuf);
  gemm_nt<0, 1><<<dim3(16, 32, 1), 256, 0, stream>>>(
      hsbuf, W_outT, out, 4096, EE, HH, HH, HH, EE,
      0, 0, 0, 0, 0, 0, nullptr, nullptr, 0, 0);
}